// Round 1
// 12958.405 us; speedup vs baseline: 1.5040x; 1.5040x over previous
//
#include <hip/hip_runtime.h>
#include <math.h>

namespace {

constexpr int kB  = 2;
constexpr int kS  = 1024;
constexpr int kD  = 1000;
constexpr int kE  = 20;
constexpr int kHD = 50;
constexpr int kF  = 2048;
constexpr int kQKV = 3 * kHD;   // 150

// ---------------------------------------------------------------- elementwise
__global__ __launch_bounds__(256) void zero_kernel(float* __restrict__ p, int n) {
    int i = blockIdx.x * 256 + threadIdx.x;
    if (i < n) p[i] = 0.0f;
}

__global__ __launch_bounds__(256) void gelu_kernel(float* __restrict__ p, int n) {
    int i = blockIdx.x * 256 + threadIdx.x;
    if (i < n) {
        float x = p[i];
        p[i] = 0.5f * x * (1.0f + erff(x * 0.70710678118654752440f));
    }
}

// seg[b][r][d] = src[b][(st+r) mod S][d]
__global__ __launch_bounds__(256) void gather_kernel(const float* __restrict__ src,
                                                     float* __restrict__ dst,
                                                     int st, int sseg) {
    int i = blockIdx.x * 256 + threadIdx.x;
    int tot = kB * sseg * kD;
    if (i >= tot) return;
    int d  = i % kD;
    int tr = i / kD;
    int r  = tr % sseg;
    int b  = tr / sseg;
    int srow = st + r;
    if (srow >= kS) srow -= kS;
    dst[i] = src[(b * kS + srow) * kD + d];
}

// dst[b][(st+r) mod S][d] += src[b][r][d]
__global__ __launch_bounds__(256) void scatter_add_kernel(const float* __restrict__ src,
                                                          float* __restrict__ dst,
                                                          int st, int sseg) {
    int i = blockIdx.x * 256 + threadIdx.x;
    int tot = kB * sseg * kD;
    if (i >= tot) return;
    int d  = i % kD;
    int tr = i / kD;
    int r  = tr % sseg;
    int b  = tr / sseg;
    int drow = st + r;
    if (drow >= kS) drow -= kS;
    dst[(b * kS + drow) * kD + d] += src[i];
}

// cur = xnew / counts
__global__ __launch_bounds__(256) void finalize_kernel(const float* __restrict__ xn,
                                                       float* __restrict__ cur) {
    int i = blockIdx.x * 256 + threadIdx.x;
    const int tot = kB * kS * kD;
    if (i >= tot) return;
    int r = (i / kD) % kS;
    float cnt = 0.0f;
    cnt += (r < 460) ? 1.0f : 0.0f;
    cnt += (r >= 256 && r < 665) ? 1.0f : 0.0f;
    cnt += (r >= 460 && r < 870) ? 1.0f : 0.0f;
    cnt += (r >= 665) ? 1.0f : 0.0f;
    cnt += (r < 51) ? 1.0f : 0.0f;
    cnt = fmaxf(cnt, 1.0f);
    cur[i] = xn[i] / cnt;
}

// ---------------------------------------------------------------- GEMM (fp32)
// C[M,N] = A[M,K] * W[K,N] + bias[N], batched over blockIdx.z via strides.
// Tile BM x BN x 16; 256 threads; each thread computes TM x TN.
// As stored transposed [BK][BM+4] (pad 4 -> conflict-free b128 frag reads).
// float4 global loads where alignment permits (K%4==0 always here; B path
// falls back to scalar when N%4 != 0, i.e. N=150 QKV).
template<int BM, int BN, int TM, int TN>
__global__ __launch_bounds__(256) void gemm_tile(
    const float* __restrict__ A, const float* __restrict__ W,
    const float* __restrict__ bias, float* __restrict__ C,
    int M, int N, int K,
    long long strideW, long long strideC, long long strideBias)
{
    constexpr int BK = 16;
    constexpr int TX = BN / TN;   // threads along N
    constexpr int TY = BM / TM;   // threads along M
    static_assert(TX * TY == 256, "block must be 256 threads");
    static_assert(TM % 4 == 0 && TN % 4 == 0, "vector frags");

    W    += (long long)blockIdx.z * strideW;
    C    += (long long)blockIdx.z * strideC;
    bias += (long long)blockIdx.z * strideBias;

    __shared__ float As[BK][BM + 4];
    __shared__ float Bs[BK][BN];

    const int tid  = threadIdx.x;
    const int tx   = tid % TX;
    const int ty   = tid / TX;
    const int row0 = blockIdx.y * BM;
    const int col0 = blockIdx.x * BN;

    const bool nvec = (N % 4) == 0;
    const bool kvec = (K % 4) == 0;

    float acc[TM][TN] = {};

    const int nk = (K + BK - 1) / BK;
    for (int t = 0; t < nk; t++) {
        const int k0 = t * BK;

        // ---- stage A tile (BM x BK) transposed into As[k][m]
        #pragma unroll
        for (int i = 0; i < BM / 64; i++) {
            int f  = tid + i * 256;        // float4 index in [0, BM*BK/4)
            int r  = f >> 2;               // tile row (BK/4 = 4 chunks per row)
            int cv = f & 3;
            int gr = row0 + r;
            int gc = k0 + cv * 4;
            float4 av = make_float4(0.f, 0.f, 0.f, 0.f);
            if (gr < M) {
                if (kvec && gc + 3 < K) {
                    av = *reinterpret_cast<const float4*>(A + (long long)gr * K + gc);
                } else {
                    float t0 = (gc + 0 < K) ? A[(long long)gr * K + gc + 0] : 0.f;
                    float t1 = (gc + 1 < K) ? A[(long long)gr * K + gc + 1] : 0.f;
                    float t2 = (gc + 2 < K) ? A[(long long)gr * K + gc + 2] : 0.f;
                    float t3 = (gc + 3 < K) ? A[(long long)gr * K + gc + 3] : 0.f;
                    av = make_float4(t0, t1, t2, t3);
                }
            }
            As[cv * 4 + 0][r] = av.x;
            As[cv * 4 + 1][r] = av.y;
            As[cv * 4 + 2][r] = av.z;
            As[cv * 4 + 3][r] = av.w;
        }

        // ---- stage B tile (BK x BN)
        if (nvec) {
            #pragma unroll
            for (int i = 0; i < BN / 64; i++) {
                int f  = tid + i * 256;        // float4 index in [0, BK*BN/4)
                int r  = f / (BN / 4);
                int cv = f % (BN / 4);
                int gr = k0 + r;
                int gc = col0 + cv * 4;
                float4 bv = make_float4(0.f, 0.f, 0.f, 0.f);
                if (gr < K) {
                    if (gc + 3 < N) {
                        bv = *reinterpret_cast<const float4*>(W + (long long)gr * N + gc);
                    } else {
                        float t0 = (gc + 0 < N) ? W[(long long)gr * N + gc + 0] : 0.f;
                        float t1 = (gc + 1 < N) ? W[(long long)gr * N + gc + 1] : 0.f;
                        float t2 = (gc + 2 < N) ? W[(long long)gr * N + gc + 2] : 0.f;
                        float t3 = (gc + 3 < N) ? W[(long long)gr * N + gc + 3] : 0.f;
                        bv = make_float4(t0, t1, t2, t3);
                    }
                }
                *reinterpret_cast<float4*>(&Bs[r][cv * 4]) = bv;
            }
        } else {
            for (int idx = tid; idx < BK * BN; idx += 256) {
                int r = idx / BN, c = idx % BN;
                int gr = k0 + r, gc = col0 + c;
                Bs[r][c] = (gr < K && gc < N) ? W[(long long)gr * N + gc] : 0.f;
            }
        }
        __syncthreads();

        // ---- micro-kernel
        #pragma unroll
        for (int kk = 0; kk < BK; kk++) {
            float a[TM], b[TN];
            #pragma unroll
            for (int i = 0; i < TM; i += 4) {
                float4 v = *reinterpret_cast<const float4*>(&As[kk][ty * TM + i]);
                a[i] = v.x; a[i + 1] = v.y; a[i + 2] = v.z; a[i + 3] = v.w;
            }
            #pragma unroll
            for (int j = 0; j < TN; j += 4) {
                float4 v = *reinterpret_cast<const float4*>(&Bs[kk][tx * TN + j]);
                b[j] = v.x; b[j + 1] = v.y; b[j + 2] = v.z; b[j + 3] = v.w;
            }
            #pragma unroll
            for (int i = 0; i < TM; i++)
                #pragma unroll
                for (int j = 0; j < TN; j++)
                    acc[i][j] = fmaf(a[i], b[j], acc[i][j]);
        }
        __syncthreads();
    }

    // ---- epilogue: bias + store
    #pragma unroll
    for (int i = 0; i < TM; i++) {
        int gr = row0 + ty * TM + i;
        if (gr >= M) continue;
        if (nvec) {
            #pragma unroll
            for (int j = 0; j < TN; j += 4) {
                int gc = col0 + tx * TN + j;
                if (gc + 3 < N) {
                    float4 bv = *reinterpret_cast<const float4*>(bias + gc);
                    float4 o  = make_float4(acc[i][j + 0] + bv.x,
                                            acc[i][j + 1] + bv.y,
                                            acc[i][j + 2] + bv.z,
                                            acc[i][j + 3] + bv.w);
                    *reinterpret_cast<float4*>(C + (long long)gr * N + gc) = o;
                } else {
                    for (int jj = 0; jj < 4; jj++) {
                        int g = gc + jj;
                        if (g < N) C[(long long)gr * N + g] = acc[i][j + jj] + bias[g];
                    }
                }
            }
        } else {
            #pragma unroll
            for (int j = 0; j < TN; j++) {
                int gc = col0 + tx * TN + j;
                if (gc < N) C[(long long)gr * N + gc] = acc[i][j] + bias[gc];
            }
        }
    }
}

template<int BM, int BN, int TM, int TN>
inline void launch_gemm(const float* A, const float* W, const float* bias, float* C,
                        int M, int N, int K, int Z,
                        long long sW, long long sC, long long sB, hipStream_t stream)
{
    dim3 grid((N + BN - 1) / BN, (M + BM - 1) / BM, Z);
    gemm_tile<BM, BN, TM, TN><<<grid, 256, 0, stream>>>(A, W, bias, C, M, N, K, sW, sC, sB);
}

// ---------------------------------------------------------------- routing
__global__ __launch_bounds__(256) void routing_kernel(
    const float* __restrict__ X, const float* __restrict__ RW,
    const float* __restrict__ RB, float* __restrict__ R, int T)
{
    int wave = (blockIdx.x * 256 + threadIdx.x) / 64;
    int lane = threadIdx.x & 63;
    if (wave >= T) return;
    const float* x = X + (long long)wave * kD;

    float xr[16];
    #pragma unroll
    for (int i = 0; i < 16; i++) {
        int d = lane + 64 * i;
        xr[i] = (d < kD) ? x[d] : 0.0f;
    }
    float r[kE];
    #pragma unroll
    for (int e = 0; e < kE; e++) {
        float acc = 0.0f;
        #pragma unroll
        for (int i = 0; i < 16; i++) {
            int d = lane + 64 * i;
            if (d < kD) acc = fmaf(xr[i], RW[d * kE + e], acc);
        }
        #pragma unroll
        for (int off = 32; off > 0; off >>= 1) acc += __shfl_xor(acc, off, 64);
        r[e] = acc + RB[e];
    }
    float m = r[0];
    #pragma unroll
    for (int e = 1; e < kE; e++) m = fmaxf(m, r[e]);
    float sum = 0.0f;
    #pragma unroll
    for (int e = 0; e < kE; e++) { r[e] = expf(r[e] - m); sum += r[e]; }
    float inv = 1.0f / sum;
    float mine = 0.0f;
    #pragma unroll
    for (int e = 0; e < kE; e++) if (lane == e) mine = r[e] * inv;
    if (lane < kE) R[(long long)wave * kE + lane] = mine;
}

// ---------------------------------------------------------------- attention
// Flash-style tiled attention. Block = (64-query tile, expert e, batch b).
// QKV layout [E][T][150] with T = kB*s; rows of this (e,b) start at b*s.
__global__ __launch_bounds__(256) void attn_kernel(
    const float* __restrict__ QKV, const float* __restrict__ R,
    float* __restrict__ O, int s)
{
    const int q0 = blockIdx.x * 64;
    const int e  = blockIdx.y;
    const int b  = blockIdx.z;
    const int T  = kB * s;
    const float* base = QKV + ((long long)e * T + (long long)b * s) * kQKV;

    __shared__ float Qs[64][51];
    __shared__ float Ks[64][51];
    __shared__ float Vs[64][51];
    __shared__ float Sb[64][65];
    __shared__ float mrow[64], lrow[64], arow[64];

    const int tid = threadIdx.x;
    const int tx = tid & 15, ty = tid >> 4;

    for (int idx = tid; idx < 64 * kHD; idx += 256) {
        int r = idx / kHD, h = idx % kHD;
        int q = q0 + r;
        Qs[r][h] = (q < s) ? base[(long long)q * kQKV + h] : 0.0f;
    }
    if (tid < 64) { mrow[tid] = -1e30f; lrow[tid] = 0.0f; }

    float o[4][4] = {};

    for (int k0 = 0; k0 < s; k0 += 64) {
        const int kn = min(64, s - k0);
        __syncthreads();
        for (int idx = tid; idx < 64 * kHD; idx += 256) {
            int r = idx / kHD, h = idx % kHD;
            const float* row = base + (long long)(k0 + r) * kQKV;
            bool ok = (r < kn);
            Ks[r][h] = ok ? row[kHD + h] : 0.0f;
            Vs[r][h] = ok ? row[2 * kHD + h] : 0.0f;
        }
        __syncthreads();

        float sacc[4][4] = {};
        for (int kk = 0; kk < kHD; kk++) {
            float a[4], bb[4];
            #pragma unroll
            for (int i = 0; i < 4; i++) a[i] = Qs[ty * 4 + i][kk];
            #pragma unroll
            for (int j = 0; j < 4; j++) bb[j] = Ks[tx * 4 + j][kk];
            #pragma unroll
            for (int i = 0; i < 4; i++)
                #pragma unroll
                for (int j = 0; j < 4; j++)
                    sacc[i][j] = fmaf(a[i], bb[j], sacc[i][j]);
        }
        #pragma unroll
        for (int i = 0; i < 4; i++)
            #pragma unroll
            for (int j = 0; j < 4; j++)
                Sb[ty * 4 + i][tx * 4 + j] = sacc[i][j] * 0.14142135623730950488f;
        __syncthreads();

        if (tid < 64) {
            float m_old = mrow[tid];
            float tmax = -1e30f;
            for (int j = 0; j < kn; j++) tmax = fmaxf(tmax, Sb[tid][j]);
            float m_new = fmaxf(m_old, tmax);
            float alpha = __expf(m_old - m_new);
            float rs = 0.0f;
            for (int j = 0; j < 64; j++) {
                float p = (j < kn) ? __expf(Sb[tid][j] - m_new) : 0.0f;
                Sb[tid][j] = p;
                rs += p;
            }
            mrow[tid] = m_new;
            lrow[tid] = lrow[tid] * alpha + rs;
            arow[tid] = alpha;
        }
        __syncthreads();

        float al[4];
        #pragma unroll
        for (int i = 0; i < 4; i++) al[i] = arow[ty * 4 + i];
        #pragma unroll
        for (int i = 0; i < 4; i++)
            #pragma unroll
            for (int j = 0; j < 4; j++)
                o[i][j] *= al[i];
        for (int j = 0; j < 64; j++) {
            float p[4], v[4];
            #pragma unroll
            for (int i = 0; i < 4; i++) p[i] = Sb[ty * 4 + i][j];
            #pragma unroll
            for (int c = 0; c < 4; c++) v[c] = Vs[j][tx * 4 + c];
            #pragma unroll
            for (int i = 0; i < 4; i++)
                #pragma unroll
                for (int c = 0; c < 4; c++)
                    o[i][c] = fmaf(p[i], v[c], o[i][c]);
        }
    }

    __syncthreads();
    #pragma unroll
    for (int i = 0; i < 4; i++)
        #pragma unroll
        for (int j = 0; j < 4; j++) {
            int h = tx * 4 + j;
            if (h < kHD) Sb[ty * 4 + i][h] = o[i][j];
        }
    __syncthreads();
    for (int idx = tid; idx < 64 * kHD; idx += 256) {
        int r = idx / kHD, h = idx % kHD;
        int q = q0 + r;
        if (q < s) {
            long long t = (long long)b * s + q;
            float scale = R[t * kE + e] / lrow[r];
            O[t * kD + e * kHD + h] = Sb[r][h] * scale;
        }
    }
}

// ---------------------------------------------------------------- layernorm
__global__ __launch_bounds__(256) void ln_kernel(
    const float* __restrict__ Xres, const float* __restrict__ A,
    const float* __restrict__ G, const float* __restrict__ Bb,
    float* __restrict__ Y)
{
    const int t = blockIdx.x;
    const float* x = Xres + (long long)t * kD;
    const float* a = A + (long long)t * kD;
    __shared__ float buf[kD];
    __shared__ float red[4];
    const int tid = threadIdx.x;

    float lsum = 0.0f;
    for (int d = tid; d < kD; d += 256) {
        float v = x[d] + a[d];
        buf[d] = v;
        lsum += v;
    }
    #pragma unroll
    for (int off = 32; off > 0; off >>= 1) lsum += __shfl_xor(lsum, off, 64);
    if ((tid & 63) == 0) red[tid >> 6] = lsum;
    __syncthreads();
    float mean = (red[0] + red[1] + red[2] + red[3]) * (1.0f / kD);

    float lv = 0.0f;
    for (int d = tid; d < kD; d += 256) {
        float u = buf[d] - mean;
        lv = fmaf(u, u, lv);
    }
    #pragma unroll
    for (int off = 32; off > 0; off >>= 1) lv += __shfl_xor(lv, off, 64);
    __syncthreads();
    if ((tid & 63) == 0) red[tid >> 6] = lv;
    __syncthreads();
    float var = (red[0] + red[1] + red[2] + red[3]) * (1.0f / kD);
    float inv = rsqrtf(var + 1e-5f);

    for (int d = tid; d < kD; d += 256)
        Y[(long long)t * kD + d] = (buf[d] - mean) * inv * G[d] + Bb[d];
}

// ---------------------------------------------------------------- host side
struct Params {
    const float *expert_w, *expert_b, *router_w, *router_b, *out_w, *out_b;
    const float *ln1_g, *ln1_b, *ff_w1, *ff_b1, *ff_w2, *ff_b2, *ln2_g, *ln2_b;
};

void run_block(const float* xin, float* xout, int s, int li, const Params& P,
               float* routing, float* qkv, float* attn_comb, float* a_out,
               float* y1, float* h, float* f, hipStream_t stream)
{
    const int T = kB * s;

    routing_kernel<<<(T + 3) / 4, 256, 0, stream>>>(
        xin, P.router_w + (long long)li * kD * kE, P.router_b + li * kE, routing, T);

    // QKV: batched over E=20 experts, N=150 (scalar B path, misaligned rows)
    launch_gemm<128, 64, 8, 4>(
        xin, P.expert_w + (long long)li * kE * kD * kQKV,
        P.expert_b + (long long)li * kE * kQKV, qkv,
        T, kQKV, kD, kE,
        (long long)kD * kQKV, (long long)T * kQKV, (long long)kQKV, stream);

    {
        dim3 grid((s + 63) / 64, kE, kB);
        attn_kernel<<<grid, 256, 0, stream>>>(qkv, routing, attn_comb, s);
    }

    // attention out-proj: M=T, N=1000, K=1000
    if (T >= 1536)
        launch_gemm<128, 64, 8, 4>(attn_comb, P.out_w + (long long)li * kD * kD,
                                   P.out_b + li * kD, a_out, T, kD, kD, 1, 0, 0, 0, stream);
    else
        launch_gemm<64, 64, 4, 4>(attn_comb, P.out_w + (long long)li * kD * kD,
                                  P.out_b + li * kD, a_out, T, kD, kD, 1, 0, 0, 0, stream);

    ln_kernel<<<T, 256, 0, stream>>>(xin, a_out, P.ln1_g + li * kD, P.ln1_b + li * kD, y1);

    // ff1: M=T, N=2048, K=1000
    if (T >= 1536)
        launch_gemm<128, 128, 8, 8>(y1, P.ff_w1 + (long long)li * kD * kF,
                                    P.ff_b1 + li * kF, h, T, kF, kD, 1, 0, 0, 0, stream);
    else
        launch_gemm<128, 64, 8, 4>(y1, P.ff_w1 + (long long)li * kD * kF,
                                   P.ff_b1 + li * kF, h, T, kF, kD, 1, 0, 0, 0, stream);

    gelu_kernel<<<(T * kF + 255) / 256, 256, 0, stream>>>(h, T * kF);

    // ff2: M=T, N=1000, K=2048
    if (T >= 1536)
        launch_gemm<128, 64, 8, 4>(h, P.ff_w2 + (long long)li * kF * kD,
                                   P.ff_b2 + li * kD, f, T, kD, kF, 1, 0, 0, 0, stream);
    else
        launch_gemm<64, 64, 4, 4>(h, P.ff_w2 + (long long)li * kF * kD,
                                  P.ff_b2 + li * kD, f, T, kD, kF, 1, 0, 0, 0, stream);

    ln_kernel<<<T, 256, 0, stream>>>(y1, f, P.ln2_g + li * kD, P.ln2_b + li * kD, xout);
}

} // namespace

extern "C" void kernel_launch(void* const* d_in, const int* in_sizes, int n_in,
                              void* d_out, int out_size, void* d_ws, size_t ws_size,
                              hipStream_t stream)
{
    const float* x = (const float*)d_in[0];
    Params P;
    P.expert_w = (const float*)d_in[1];
    P.expert_b = (const float*)d_in[2];
    P.router_w = (const float*)d_in[3];
    P.router_b = (const float*)d_in[4];
    P.out_w    = (const float*)d_in[5];
    P.out_b    = (const float*)d_in[6];
    P.ln1_g    = (const float*)d_in[7];
    P.ln1_b    = (const float*)d_in[8];
    P.ff_w1    = (const float*)d_in[9];
    P.ff_b1    = (const float*)d_in[10];
    P.ff_w2    = (const float*)d_in[11];
    P.ff_b2    = (const float*)d_in[12];
    P.ln2_g    = (const float*)d_in[13];
    P.ln2_b    = (const float*)d_in[14];

    const int TD = kB * kS * kD;
    float* ws = (float*)d_ws;
    float* cur       = ws;  ws += TD;
    float* xnew      = ws;  ws += TD;
    float* seg       = ws;  ws += TD;
    float* routing   = ws;  ws += kB * kS * kE;
    float* qkv       = ws;  ws += kE * kB * kS * kQKV;
    float* attn_comb = ws;  ws += TD;
    float* a_out     = ws;  ws += TD;
    float* y1        = ws;  ws += TD;
    float* h         = ws;  ws += kB * kS * kF;
    float* f         = ws;  ws += TD;
    float* bout      = (float*)d_out;

    run_block(x, cur, kS, 0, P, routing, qkv, attn_comb, a_out, y1, h, f, stream);

    const int st_arr[4]  = {0, 256, 460, 665};
    const int len_arr[4] = {460, 409, 410, 410};

    for (int c = 0; c < 3; c++) {
        zero_kernel<<<(TD + 255) / 256, 256, 0, stream>>>(xnew, TD);
        for (int j = 0; j < 4; j++) {
            const int st = st_arr[j], sl = len_arr[j];
            const int li = 1 + 4 * c + j;
            const int n = kB * sl * kD;
            gather_kernel<<<(n + 255) / 256, 256, 0, stream>>>(cur, seg, st, sl);
            run_block(seg, bout, sl, li, P, routing, qkv, attn_comb, a_out, y1, h, f, stream);
            scatter_add_kernel<<<(n + 255) / 256, 256, 0, stream>>>(bout, xnew, st, sl);
        }
        finalize_kernel<<<(TD + 255) / 256, 256, 0, stream>>>(xnew, cur);
    }

    run_block(cur, (float*)d_out, kS, 13, P, routing, qkv, attn_comb, a_out, y1, h, f, stream);
}

// Round 2
// 10561.293 us; speedup vs baseline: 1.8453x; 1.2270x over previous
//
#include <hip/hip_runtime.h>
#include <math.h>

namespace {

constexpr int kB  = 2;
constexpr int kS  = 1024;
constexpr int kD  = 1000;
constexpr int kE  = 20;
constexpr int kHD = 50;
constexpr int kF  = 2048;
constexpr int kQKV = 3 * kHD;   // 150

// ---------------------------------------------------------------- elementwise
__global__ __launch_bounds__(256) void zero_kernel(float* __restrict__ p, int n) {
    int i = blockIdx.x * 256 + threadIdx.x;
    if (i < n) p[i] = 0.0f;
}

__global__ __launch_bounds__(256) void gelu_kernel(float* __restrict__ p, int n) {
    int i = blockIdx.x * 256 + threadIdx.x;
    if (i < n) {
        float x = p[i];
        p[i] = 0.5f * x * (1.0f + erff(x * 0.70710678118654752440f));
    }
}

__global__ __launch_bounds__(256) void init_bias_kernel(float* __restrict__ C,
                                                        const float* __restrict__ bias,
                                                        long long total, int N) {
    long long i = (long long)blockIdx.x * 256 + threadIdx.x;
    if (i < total) C[i] = bias[(int)(i % N)];
}

// seg[b][r][d] = src[b][(st+r) mod S][d]
__global__ __launch_bounds__(256) void gather_kernel(const float* __restrict__ src,
                                                     float* __restrict__ dst,
                                                     int st, int sseg) {
    int i = blockIdx.x * 256 + threadIdx.x;
    int tot = kB * sseg * kD;
    if (i >= tot) return;
    int d  = i % kD;
    int tr = i / kD;
    int r  = tr % sseg;
    int b  = tr / sseg;
    int srow = st + r;
    if (srow >= kS) srow -= kS;
    dst[i] = src[(b * kS + srow) * kD + d];
}

// dst[b][(st+r) mod S][d] += src[b][r][d]
__global__ __launch_bounds__(256) void scatter_add_kernel(const float* __restrict__ src,
                                                          float* __restrict__ dst,
                                                          int st, int sseg) {
    int i = blockIdx.x * 256 + threadIdx.x;
    int tot = kB * sseg * kD;
    if (i >= tot) return;
    int d  = i % kD;
    int tr = i / kD;
    int r  = tr % sseg;
    int b  = tr / sseg;
    int drow = st + r;
    if (drow >= kS) drow -= kS;
    dst[(b * kS + drow) * kD + d] += src[i];
}

// cur = xnew / counts
__global__ __launch_bounds__(256) void finalize_kernel(const float* __restrict__ xn,
                                                       float* __restrict__ cur) {
    int i = blockIdx.x * 256 + threadIdx.x;
    const int tot = kB * kS * kD;
    if (i >= tot) return;
    int r = (i / kD) % kS;
    float cnt = 0.0f;
    cnt += (r < 460) ? 1.0f : 0.0f;
    cnt += (r >= 256 && r < 665) ? 1.0f : 0.0f;
    cnt += (r >= 460 && r < 870) ? 1.0f : 0.0f;
    cnt += (r >= 665) ? 1.0f : 0.0f;
    cnt += (r < 51) ? 1.0f : 0.0f;
    cnt = fmaxf(cnt, 1.0f);
    cur[i] = xn[i] / cnt;
}

// ---------------------------------------------------------------- GEMM (fp32)
// C[M,N] = A[M,K] * W[K,N] + bias[N].
// NMAP > 0: expert-blocked B/C remap (QKV): element (k, gc) of B lives at
//   W[e*K*NMAP + k*NMAP + n], C at C[e*M*NMAP + gr*NMAP + n], e=gc/NMAP.
// ATOMIC: blockIdx.z = split-K chunk; epilogue atomicAdd, bias pre-applied
//   via init_bias_kernel.  Otherwise blockIdx.z = batch via strides.
template<int BM, int BN, int TM, int TN, int NMAP, bool ATOMIC>
__global__ __launch_bounds__(256) void gemm_tile(
    const float* __restrict__ A, const float* __restrict__ W,
    const float* __restrict__ bias, float* __restrict__ C,
    int M, int N, int K, int kchunk,
    long long strideW, long long strideC, long long strideBias)
{
    constexpr int BK = 16;
    constexpr int TX = BN / TN;   // threads along N
    constexpr int TY = BM / TM;   // threads along M
    static_assert(TX * TY == 256, "block must be 256 threads");
    static_assert(TM % 4 == 0 && TN % 4 == 0, "vector frags");

    int kbeg = 0, kend = K;
    if (ATOMIC) {
        kbeg = blockIdx.z * kchunk;
        kend = min(K, kbeg + kchunk);
    } else {
        W    += (long long)blockIdx.z * strideW;
        C    += (long long)blockIdx.z * strideC;
        bias += (long long)blockIdx.z * strideBias;
    }

    __shared__ __align__(16) float As[BK][BM + 4];
    __shared__ __align__(16) float Bs[BK][BN];

    const int tid  = threadIdx.x;
    const int tx   = tid % TX;
    const int ty   = tid / TX;
    const int row0 = blockIdx.y * BM;
    const int col0 = blockIdx.x * BN;

    float acc[TM][TN] = {};

    for (int k0 = kbeg; k0 < kend; k0 += BK) {
        // ---- stage A tile (BM x BK) transposed into As[k][m]
        #pragma unroll
        for (int i = 0; i < BM / 64; i++) {
            int f  = tid + i * 256;
            int r  = f >> 2;
            int cv = f & 3;
            int gr = row0 + r;
            int gc = k0 + cv * 4;
            float4 av = make_float4(0.f, 0.f, 0.f, 0.f);
            if (gr < M) {
                if (gc + 3 < kend) {
                    av = *reinterpret_cast<const float4*>(A + (long long)gr * K + gc);
                } else {
                    float t0 = (gc + 0 < kend) ? A[(long long)gr * K + gc + 0] : 0.f;
                    float t1 = (gc + 1 < kend) ? A[(long long)gr * K + gc + 1] : 0.f;
                    float t2 = (gc + 2 < kend) ? A[(long long)gr * K + gc + 2] : 0.f;
                    float t3 = (gc + 3 < kend) ? A[(long long)gr * K + gc + 3] : 0.f;
                    av = make_float4(t0, t1, t2, t3);
                }
            }
            As[cv * 4 + 0][r] = av.x;
            As[cv * 4 + 1][r] = av.y;
            As[cv * 4 + 2][r] = av.z;
            As[cv * 4 + 3][r] = av.w;
        }

        // ---- stage B tile (BK x BN)
        if (NMAP > 0) {
            #pragma unroll
            for (int it = 0; it < (BK * BN) / 256; it++) {
                int idx = tid + it * 256;
                int r = idx / BN, c = idx % BN;
                int gr = k0 + r, gc = col0 + c;
                float v = 0.f;
                if (gr < kend && gc < N) {
                    int e = gc / NMAP;
                    int n = gc - e * NMAP;
                    v = W[(long long)e * K * NMAP + (long long)gr * NMAP + n];
                }
                Bs[r][c] = v;
            }
        } else {
            #pragma unroll
            for (int i = 0; i < BN / 64; i++) {
                int f  = tid + i * 256;
                int r  = f / (BN / 4);
                int cv = f % (BN / 4);
                int gr = k0 + r;
                int gc = col0 + cv * 4;
                float4 bv = make_float4(0.f, 0.f, 0.f, 0.f);
                if (gr < kend) {
                    if (gc + 3 < N) {
                        bv = *reinterpret_cast<const float4*>(W + (long long)gr * N + gc);
                    } else {
                        float t0 = (gc + 0 < N) ? W[(long long)gr * N + gc + 0] : 0.f;
                        float t1 = (gc + 1 < N) ? W[(long long)gr * N + gc + 1] : 0.f;
                        float t2 = (gc + 2 < N) ? W[(long long)gr * N + gc + 2] : 0.f;
                        float t3 = (gc + 3 < N) ? W[(long long)gr * N + gc + 3] : 0.f;
                        bv = make_float4(t0, t1, t2, t3);
                    }
                }
                *reinterpret_cast<float4*>(&Bs[r][cv * 4]) = bv;
            }
        }
        __syncthreads();

        // ---- micro-kernel
        #pragma unroll
        for (int kk = 0; kk < BK; kk++) {
            float a[TM], b[TN];
            #pragma unroll
            for (int i = 0; i < TM; i += 4) {
                float4 v = *reinterpret_cast<const float4*>(&As[kk][ty * TM + i]);
                a[i] = v.x; a[i + 1] = v.y; a[i + 2] = v.z; a[i + 3] = v.w;
            }
            #pragma unroll
            for (int j = 0; j < TN; j += 4) {
                float4 v = *reinterpret_cast<const float4*>(&Bs[kk][tx * TN + j]);
                b[j] = v.x; b[j + 1] = v.y; b[j + 2] = v.z; b[j + 3] = v.w;
            }
            #pragma unroll
            for (int i = 0; i < TM; i++)
                #pragma unroll
                for (int j = 0; j < TN; j++)
                    acc[i][j] = fmaf(a[i], b[j], acc[i][j]);
        }
        __syncthreads();
    }

    // ---- epilogue
    #pragma unroll
    for (int i = 0; i < TM; i++) {
        int gr = row0 + ty * TM + i;
        if (gr >= M) continue;
        if (ATOMIC) {
            #pragma unroll
            for (int j = 0; j < TN; j++) {
                int gc = col0 + tx * TN + j;
                if (gc < N) atomicAdd(&C[(long long)gr * N + gc], acc[i][j]);
            }
        } else if (NMAP > 0) {
            #pragma unroll
            for (int j = 0; j < TN; j++) {
                int gc = col0 + tx * TN + j;
                if (gc < N) {
                    int e = gc / NMAP;
                    int n = gc - e * NMAP;
                    C[(long long)e * M * NMAP + (long long)gr * NMAP + n] =
                        acc[i][j] + bias[gc];
                }
            }
        } else {
            #pragma unroll
            for (int j = 0; j < TN; j += 4) {
                int gc = col0 + tx * TN + j;
                if (gc + 3 < N) {
                    float4 bv = *reinterpret_cast<const float4*>(bias + gc);
                    float4 o  = make_float4(acc[i][j + 0] + bv.x,
                                            acc[i][j + 1] + bv.y,
                                            acc[i][j + 2] + bv.z,
                                            acc[i][j + 3] + bv.w);
                    *reinterpret_cast<float4*>(C + (long long)gr * N + gc) = o;
                } else {
                    for (int jj = 0; jj < 4; jj++) {
                        int g = gc + jj;
                        if (g < N) C[(long long)gr * N + g] = acc[i][j + jj] + bias[g];
                    }
                }
            }
        }
    }
}

inline int pick_split(int gx, int gy, int K) {
    int blocks = gx * gy;
    int S = (512 + blocks - 1) / blocks;
    if (S < 1) S = 1;
    if (S > 4) S = 4;
    while (S > 1 && (K + S - 1) / S < 64) S--;
    return S;
}

// single-matrix GEMM with automatic split-K when the grid is small
inline void gemm_auto(const float* A, const float* W, const float* bias, float* C,
                      int M, int N, int K, hipStream_t stream)
{
    constexpr int BM = 128, BN = 64, TM = 8, TN = 4;
    int gx = (N + BN - 1) / BN, gy = (M + BM - 1) / BM;
    int S = pick_split(gx, gy, K);
    if (S == 1) {
        dim3 grid(gx, gy, 1);
        gemm_tile<BM, BN, TM, TN, 0, false><<<grid, 256, 0, stream>>>(
            A, W, bias, C, M, N, K, K, 0, 0, 0);
    } else {
        long long total = (long long)M * N;
        init_bias_kernel<<<(unsigned)((total + 255) / 256), 256, 0, stream>>>(
            C, bias, total, N);
        int Kc = ((K + S - 1) / S + 15) & ~15;
        dim3 grid(gx, gy, S);
        gemm_tile<BM, BN, TM, TN, 0, true><<<grid, 256, 0, stream>>>(
            A, W, nullptr, C, M, N, K, Kc, 0, 0, 0);
    }
}

// ---------------------------------------------------------------- routing
__global__ __launch_bounds__(256) void routing_kernel(
    const float* __restrict__ X, const float* __restrict__ RW,
    const float* __restrict__ RB, float* __restrict__ R, int T)
{
    int wave = (blockIdx.x * 256 + threadIdx.x) / 64;
    int lane = threadIdx.x & 63;
    if (wave >= T) return;
    const float* x = X + (long long)wave * kD;

    float xr[16];
    #pragma unroll
    for (int i = 0; i < 16; i++) {
        int d = lane + 64 * i;
        xr[i] = (d < kD) ? x[d] : 0.0f;
    }
    float r[kE];
    #pragma unroll
    for (int e = 0; e < kE; e++) {
        float acc = 0.0f;
        #pragma unroll
        for (int i = 0; i < 16; i++) {
            int d = lane + 64 * i;
            if (d < kD) acc = fmaf(xr[i], RW[d * kE + e], acc);
        }
        #pragma unroll
        for (int off = 32; off > 0; off >>= 1) acc += __shfl_xor(acc, off, 64);
        r[e] = acc + RB[e];
    }
    float m = r[0];
    #pragma unroll
    for (int e = 1; e < kE; e++) m = fmaxf(m, r[e]);
    float sum = 0.0f;
    #pragma unroll
    for (int e = 0; e < kE; e++) { r[e] = expf(r[e] - m); sum += r[e]; }
    float inv = 1.0f / sum;
    float mine = 0.0f;
    #pragma unroll
    for (int e = 0; e < kE; e++) if (lane == e) mine = r[e] * inv;
    if (lane < kE) R[(long long)wave * kE + lane] = mine;
}

// ---------------------------------------------------------------- attention
// Flash-style. Block = (64-query tile, expert e, batch b). 256 threads,
// micro-tile 4x4 (ty row-group 0..15, tx col-group 0..15).
// Q/K staged transposed for float4 fragment reads; softmax fully in
// registers via 16-lane shfl row-reductions; P written to LDS (union with
// Kt) as aligned float4 rows; PV in float4 chunks.
constexpr int QT_STR = 68;   // Q^T/K^T row stride (mult of 4, 16B aligned)
constexpr int VS_STR = 52;   // V row stride
constexpr int SB_STR = 68;   // P row stride

__global__ __launch_bounds__(256) void attn_kernel(
    const float* __restrict__ QKV, const float* __restrict__ R,
    float* __restrict__ O, int s)
{
    const int q0 = blockIdx.x * 64;
    const int e  = blockIdx.y;
    const int b  = blockIdx.z;
    const int T  = kB * s;
    const float* base = QKV + ((long long)e * T + (long long)b * s) * kQKV;

    __shared__ __align__(16) float Qt[kHD * QT_STR];   // Q^T [h][row]
    __shared__ __align__(16) float Vs[64 * VS_STR];    // V row-major
    __shared__ __align__(16) float KS[64 * SB_STR];    // union: K^T [50][68] / P [64][68]

    const int tid = threadIdx.x;
    const int tx  = tid & 15;
    const int ty  = tid >> 4;
    const int row = ty * 4;          // first of this thread's 4 rows

    // stage Q transposed (coalesced global read)
    for (int idx = tid; idx < 64 * kHD; idx += 256) {
        int r = idx / kHD, h = idx % kHD;
        int q = q0 + r;
        Qt[h * QT_STR + r] = (q < s) ? base[(long long)q * kQKV + h] : 0.0f;
    }

    float o[4][4] = {};
    float m[4] = {-1e30f, -1e30f, -1e30f, -1e30f};
    float l[4] = {};

    const int ntile = (s + 63) / 64;
    for (int t = 0; t < ntile; t++) {
        const int k0 = t * 64;
        const int kn = min(64, s - k0);

        __syncthreads();   // (A) prev PV done with Vs/KS; Qt visible (t=0)
        for (int idx = tid; idx < 64 * kHD; idx += 256) {
            int r = idx / kHD, h = idx % kHD;
            const float* rowp = base + (long long)(k0 + r) * kQKV;
            bool ok = (r < kn);
            KS[h * SB_STR + r]  = ok ? rowp[kHD + h] : 0.0f;
            Vs[r * VS_STR + h]  = ok ? rowp[2 * kHD + h] : 0.0f;
        }
        __syncthreads();   // (B) staging visible

        // scores: 64x64 tile, K-dim = 50, float4 fragments
        float sacc[4][4] = {};
        #pragma unroll 2
        for (int kk = 0; kk < kHD; kk++) {
            float4 a4 = *reinterpret_cast<const float4*>(&Qt[kk * QT_STR + row]);
            float4 b4 = *reinterpret_cast<const float4*>(&KS[kk * SB_STR + tx * 4]);
            const float av[4] = {a4.x, a4.y, a4.z, a4.w};
            const float bv[4] = {b4.x, b4.y, b4.z, b4.w};
            #pragma unroll
            for (int i = 0; i < 4; i++)
                #pragma unroll
                for (int j = 0; j < 4; j++)
                    sacc[i][j] = fmaf(av[i], bv[j], sacc[i][j]);
        }

        // in-register online softmax (16-lane row reductions)
        #pragma unroll
        for (int i = 0; i < 4; i++) {
            #pragma unroll
            for (int j = 0; j < 4; j++) {
                float v = sacc[i][j] * 0.14142135623730950488f;
                sacc[i][j] = (tx * 4 + j < kn) ? v : -1e30f;
            }
            float rm = fmaxf(fmaxf(sacc[i][0], sacc[i][1]),
                             fmaxf(sacc[i][2], sacc[i][3]));
            rm = fmaxf(rm, __shfl_xor(rm, 1, 64));
            rm = fmaxf(rm, __shfl_xor(rm, 2, 64));
            rm = fmaxf(rm, __shfl_xor(rm, 4, 64));
            rm = fmaxf(rm, __shfl_xor(rm, 8, 64));
            float mn = fmaxf(m[i], rm);
            float alpha = __expf(m[i] - mn);
            m[i] = mn;
            float rs = 0.0f;
            #pragma unroll
            for (int j = 0; j < 4; j++) {
                float p = __expf(sacc[i][j] - mn);
                sacc[i][j] = p;
                rs += p;
            }
            rs += __shfl_xor(rs, 1, 64);
            rs += __shfl_xor(rs, 2, 64);
            rs += __shfl_xor(rs, 4, 64);
            rs += __shfl_xor(rs, 8, 64);
            l[i] = l[i] * alpha + rs;
            #pragma unroll
            for (int c = 0; c < 4; c++) o[i][c] *= alpha;
        }

        __syncthreads();   // (C) all lanes done reading KS as K^T
        #pragma unroll
        for (int i = 0; i < 4; i++)
            *reinterpret_cast<float4*>(&KS[(row + i) * SB_STR + tx * 4]) =
                make_float4(sacc[i][0], sacc[i][1], sacc[i][2], sacc[i][3]);
        __syncthreads();   // (D) P visible

        // PV: o += P * V, float4 chunks over key dim
        #pragma unroll 2
        for (int j0 = 0; j0 < 64; j0 += 4) {
            float4 pr[4], vr[4];
            #pragma unroll
            for (int i = 0; i < 4; i++)
                pr[i] = *reinterpret_cast<const float4*>(&KS[(row + i) * SB_STR + j0]);
            #pragma unroll
            for (int jj = 0; jj < 4; jj++)
                vr[jj] = *reinterpret_cast<const float4*>(&Vs[(j0 + jj) * VS_STR + tx * 4]);
            #pragma unroll
            for (int i = 0; i < 4; i++) {
                const float pv[4] = {pr[i].x, pr[i].y, pr[i].z, pr[i].w};
                #pragma unroll
                for (int jj = 0; jj < 4; jj++) {
                    o[i][0] = fmaf(pv[jj], vr[jj].x, o[i][0]);
                    o[i][1] = fmaf(pv[jj], vr[jj].y, o[i][1]);
                    o[i][2] = fmaf(pv[jj], vr[jj].z, o[i][2]);
                    o[i][3] = fmaf(pv[jj], vr[jj].w, o[i][3]);
                }
            }
        }
    }

    // epilogue: scale by routing/l, direct store (head-combine layout)
    const int hbase = tx * 4;
    if (hbase < kHD) {
        #pragma unroll
        for (int i = 0; i < 4; i++) {
            int q = q0 + row + i;
            if (q >= s) continue;
            long long tok = (long long)b * s + q;
            float sc = R[tok * kE + e] / l[i];
            float* op = O + tok * kD + e * kHD + hbase;
            if (hbase + 3 < kHD) {
                *reinterpret_cast<float2*>(op) =
                    make_float2(o[i][0] * sc, o[i][1] * sc);
                *reinterpret_cast<float2*>(op + 2) =
                    make_float2(o[i][2] * sc, o[i][3] * sc);
            } else {   // tx == 12: cols 48,49
                op[0] = o[i][0] * sc;
                op[1] = o[i][1] * sc;
            }
        }
    }
}

// ---------------------------------------------------------------- layernorm
__global__ __launch_bounds__(256) void ln_kernel(
    const float* __restrict__ Xres, const float* __restrict__ A,
    const float* __restrict__ G, const float* __restrict__ Bb,
    float* __restrict__ Y)
{
    const int t = blockIdx.x;
    const float* x = Xres + (long long)t * kD;
    const float* a = A + (long long)t * kD;
    __shared__ float buf[kD];
    __shared__ float red[4];
    const int tid = threadIdx.x;

    float lsum = 0.0f;
    for (int d = tid; d < kD; d += 256) {
        float v = x[d] + a[d];
        buf[d] = v;
        lsum += v;
    }
    #pragma unroll
    for (int off = 32; off > 0; off >>= 1) lsum += __shfl_xor(lsum, off, 64);
    if ((tid & 63) == 0) red[tid >> 6] = lsum;
    __syncthreads();
    float mean = (red[0] + red[1] + red[2] + red[3]) * (1.0f / kD);

    float lv = 0.0f;
    for (int d = tid; d < kD; d += 256) {
        float u = buf[d] - mean;
        lv = fmaf(u, u, lv);
    }
    #pragma unroll
    for (int off = 32; off > 0; off >>= 1) lv += __shfl_xor(lv, off, 64);
    __syncthreads();
    if ((tid & 63) == 0) red[tid >> 6] = lv;
    __syncthreads();
    float var = (red[0] + red[1] + red[2] + red[3]) * (1.0f / kD);
    float inv = rsqrtf(var + 1e-5f);

    for (int d = tid; d < kD; d += 256)
        Y[(long long)t * kD + d] = (buf[d] - mean) * inv * G[d] + Bb[d];
}

// ---------------------------------------------------------------- host side
struct Params {
    const float *expert_w, *expert_b, *router_w, *router_b, *out_w, *out_b;
    const float *ln1_g, *ln1_b, *ff_w1, *ff_b1, *ff_w2, *ff_b2, *ln2_g, *ln2_b;
};

void run_block(const float* xin, float* xout, int s, int li, const Params& P,
               float* routing, float* qkv, float* attn_comb, float* a_out,
               float* y1, float* h, float* f, hipStream_t stream)
{
    const int T = kB * s;

    routing_kernel<<<(T + 3) / 4, 256, 0, stream>>>(
        xin, P.router_w + (long long)li * kD * kE, P.router_b + li * kE, routing, T);

    // QKV merged across experts: M=T, N=E*150=3000, K=1000, NMAP=150
    {
        dim3 grid((kE * kQKV + 63) / 64, (T + 127) / 128, 1);
        gemm_tile<128, 64, 8, 4, kQKV, false><<<grid, 256, 0, stream>>>(
            xin, P.expert_w + (long long)li * kE * kD * kQKV,
            P.expert_b + (long long)li * kE * kQKV, qkv,
            T, kE * kQKV, kD, kD, 0, 0, 0);
    }

    {
        dim3 grid((s + 63) / 64, kE, kB);
        attn_kernel<<<grid, 256, 0, stream>>>(qkv, routing, attn_comb, s);
    }

    // attention out-proj: M=T, N=1000, K=1000 (split-K when grid small)
    gemm_auto(attn_comb, P.out_w + (long long)li * kD * kD,
              P.out_b + li * kD, a_out, T, kD, kD, stream);

    ln_kernel<<<T, 256, 0, stream>>>(xin, a_out, P.ln1_g + li * kD, P.ln1_b + li * kD, y1);

    // ff1: M=T, N=2048, K=1000
    gemm_auto(y1, P.ff_w1 + (long long)li * kD * kF,
              P.ff_b1 + li * kF, h, T, kF, kD, stream);

    gelu_kernel<<<(T * kF + 255) / 256, 256, 0, stream>>>(h, T * kF);

    // ff2: M=T, N=1000, K=2048
    gemm_auto(h, P.ff_w2 + (long long)li * kF * kD,
              P.ff_b2 + li * kD, f, T, kD, kF, stream);

    ln_kernel<<<T, 256, 0, stream>>>(y1, f, P.ln2_g + li * kD, P.ln2_b + li * kD, xout);
}

} // namespace

extern "C" void kernel_launch(void* const* d_in, const int* in_sizes, int n_in,
                              void* d_out, int out_size, void* d_ws, size_t ws_size,
                              hipStream_t stream)
{
    const float* x = (const float*)d_in[0];
    Params P;
    P.expert_w = (const float*)d_in[1];
    P.expert_b = (const float*)d_in[2];
    P.router_w = (const float*)d_in[3];
    P.router_b = (const float*)d_in[4];
    P.out_w    = (const float*)d_in[5];
    P.out_b    = (const float*)d_in[6];
    P.ln1_g    = (const float*)d_in[7];
    P.ln1_b    = (const float*)d_in[8];
    P.ff_w1    = (const float*)d_in[9];
    P.ff_b1    = (const float*)d_in[10];
    P.ff_w2    = (const float*)d_in[11];
    P.ff_b2    = (const float*)d_in[12];
    P.ln2_g    = (const float*)d_in[13];
    P.ln2_b    = (const float*)d_in[14];

    const int TD = kB * kS * kD;
    float* ws = (float*)d_ws;
    float* cur       = ws;  ws += TD;
    float* xnew      = ws;  ws += TD;
    float* seg       = ws;  ws += TD;
    float* routing   = ws;  ws += kB * kS * kE;
    float* qkv       = ws;  ws += kE * kB * kS * kQKV;
    float* attn_comb = ws;  ws += TD;
    float* a_out     = ws;  ws += TD;
    float* y1        = ws;  ws += TD;
    float* h         = ws;  ws += kB * kS * kF;
    float* f         = ws;  ws += TD;
    float* bout      = (float*)d_out;

    run_block(x, cur, kS, 0, P, routing, qkv, attn_comb, a_out, y1, h, f, stream);

    const int st_arr[4]  = {0, 256, 460, 665};
    const int len_arr[4] = {460, 409, 410, 410};

    for (int c = 0; c < 3; c++) {
        zero_kernel<<<(TD + 255) / 256, 256, 0, stream>>>(xnew, TD);
        for (int j = 0; j < 4; j++) {
            const int st = st_arr[j], sl = len_arr[j];
            const int li = 1 + 4 * c + j;
            const int n = kB * sl * kD;
            gather_kernel<<<(n + 255) / 256, 256, 0, stream>>>(cur, seg, st, sl);
            run_block(seg, bout, sl, li, P, routing, qkv, attn_comb, a_out, y1, h, f, stream);
            scatter_add_kernel<<<(n + 255) / 256, 256, 0, stream>>>(bout, xnew, st, sl);
        }
        finalize_kernel<<<(TD + 255) / 256, 256, 0, stream>>>(xnew, cur);
    }

    run_block(cur, (float*)d_out, kS, 13, P, routing, qkv, attn_comb, a_out, y1, h, f, stream);
}